// Round 4
// baseline (361.890 us; speedup 1.0000x reference)
//
#include <hip/hip_runtime.h>
#include <hip/hip_bf16.h>

#define BATCH 16
#define CIN   512
#define HW    3136
#define CM    512
#define CN    128

typedef short short8 __attribute__((ext_vector_type(8)));
typedef float f32x4  __attribute__((ext_vector_type(4)));

#define MFMA(a,b,c) __builtin_amdgcn_mfma_f32_16x16x32_bf16((a),(b),(c),0,0,0)

// Workgroup barrier WITHOUT the vmcnt(0) drain __syncthreads() emits.
__device__ __forceinline__ void wg_barrier() {
  asm volatile("s_waitcnt lgkmcnt(0)" ::: "memory");
  __builtin_amdgcn_s_barrier();
  asm volatile("" ::: "memory");
}

// convert 8 consecutive fp32 -> 8 bf16, store as one 16B chunk (LDS or global)
__device__ __forceinline__ void cvt_store8(__bf16* dst, const float* src) {
  const f32x4 a = *(const f32x4*)src;
  const f32x4 b = *(const f32x4*)(src + 4);
  __attribute__((aligned(16))) __bf16 t[8];
  t[0] = (__bf16)a[0]; t[1] = (__bf16)a[1]; t[2] = (__bf16)a[2]; t[3] = (__bf16)a[3];
  t[4] = (__bf16)b[0]; t[5] = (__bf16)b[1]; t[6] = (__bf16)b[2]; t[7] = (__bf16)b[3];
  *(uint4*)dst = *(uint4*)t;
}

// two f32x4 (in regs) -> short8 bf16 fragment
__device__ __forceinline__ short8 cvt_frag(f32x4 a, f32x4 b) {
  union { __bf16 h[8]; short8 s; } u;
  u.h[0] = (__bf16)a[0]; u.h[1] = (__bf16)a[1]; u.h[2] = (__bf16)a[2]; u.h[3] = (__bf16)a[3];
  u.h[4] = (__bf16)b[0]; u.h[5] = (__bf16)b[1]; u.h[6] = (__bf16)b[2]; u.h[7] = (__bf16)b[3];
  return u.s;
}

// ---------------------------------------------------------------------------
// Kernel 0a: pre-convert (wB|wV) fp32 -> bf16 in MFMA-fragment order.
// Chunk gid = st*2048 + w*512 + mi*128 + kk*64 + lane (16B per chunk):
//   holds W[w*64+mi*16+(lane&15)][st*64+kk*32+(lane>>4)*8 .. +8]
// ---------------------------------------------------------------------------
__global__ __launch_bounds__(256) void prep_w_kernel(
    const float* __restrict__ wB, const float* __restrict__ wV,
    __bf16* __restrict__ Wimg)
{
  const int gid  = blockIdx.x * 256 + threadIdx.x;   // 0..16383
  const int lane = gid & 63;
  const int kk   = (gid >> 6) & 1;
  const int mi   = (gid >> 7) & 3;
  const int w    = (gid >> 9) & 3;
  const int st   = (gid >> 11) & 7;
  const int row  = w*64 + mi*16 + (lane & 15);
  const int col  = st*64 + kk*32 + (lane >> 4)*8;
  const float* src = (row < 128) ? (wB + (size_t)row * CIN)
                                 : (wV + (size_t)(row - 128) * CIN);
  cvt_store8(Wimg + (size_t)gid * 8, src + col);
}

// ---------------------------------------------------------------------------
// Kernel 0b: transpose+convert x fp32 -> bf16 fragment-ordered images.
// Image (b, s-tile sx, k-step st) = 8192 B: chunk ch = (si*2+kk)*64 + lane
// holds xT[s0+si*16+(lane&15)][st*64 + kk*32 + (lane>>4)*8 .. +8].
// Block: stage a [64c][64s] chunk to LDS (coalesced fp32 reads), then emit
// the transposed image with perfectly coalesced 16B writes.
// ---------------------------------------------------------------------------
__global__ __launch_bounds__(256) void prep_x_kernel(
    const float* __restrict__ x, __bf16* __restrict__ Ximg)
{
  const int sx = blockIdx.x, st = blockIdx.y, b = blockIdx.z;
  const int s0 = sx*64, c0 = st*64;
  const int tid = threadIdx.x;
  __shared__ __attribute__((aligned(16))) __bf16 Lp[64*80]; // [c][s] pad 80

  {
    const int c_l = tid >> 2, s_q = tid & 3;
    const float* src = x + ((size_t)(b*CIN + c0 + c_l))*HW + s0 + s_q*16;
    cvt_store8(&Lp[c_l*80 + s_q*16], src);
    cvt_store8(&Lp[c_l*80 + s_q*16 + 8], src + 8);
  }
  __syncthreads();
  __bf16* img = Ximg + (((size_t)b*49 + sx)*8 + st)*4096;  // 4096 elems = 8192 B
  #pragma unroll
  for (int r = 0; r < 2; ++r) {
    const int ch = tid + 256*r;
    const int lane = ch & 63, si2kk = ch >> 6;
    const int si = si2kk >> 1, kk = si2kk & 1;
    const int qq = lane >> 4, ll = lane & 15;
    const int s_l = si*16 + ll;
    const int cb = (kk*4 + qq)*8;
    __attribute__((aligned(16))) __bf16 t[8];
    #pragma unroll
    for (int j = 0; j < 8; ++j) t[j] = Lp[(cb + j)*80 + s_l];
    *(uint4*)&img[ch*8] = *(uint4*)t;
  }
}

// ---------------------------------------------------------------------------
// Kernel 1: conv (wB|wV) @ x + bias, fused V-softmax (attVT out) and
// B-softmax row sums (atomics). BARRIER-FREE K-loop: both operands are
// fragment-ordered bf16 images; all fragments load straight to registers
// (16 coalesced 1-KB loads + 32 MFMA per step, double-buffered).
// ---------------------------------------------------------------------------
__global__ __launch_bounds__(256) void conv_bv_kernel(
    const __bf16* __restrict__ Ximg, const __bf16* __restrict__ Wimg,
    const float* __restrict__ bB, const float* __restrict__ bV,
    __bf16* __restrict__ BVB, __bf16* __restrict__ attVT,
    float* __restrict__ bsum)
{
  const int s0  = blockIdx.x * 64;
  const int b   = blockIdx.y;
  const int tid = threadIdx.x;
  const int lane = tid & 63, w = tid >> 6;
  const int l15  = lane & 15, q = lane >> 4;

  __shared__ float Vm[2][64];
  __shared__ float Vs[2][64];
  __shared__ __attribute__((aligned(16))) __bf16 T[64*136];  // 17408 B

  f32x4 acc[4][4] = {};
  const char* wb_ = (const char*)Wimg + (size_t)w*8192 + (size_t)lane*16;
  const char* xb_ = (const char*)Ximg + ((size_t)b*49 + blockIdx.x)*65536
                    + (size_t)lane*16;

  short8 wf[2][8], xf[2][8];
#define WLOAD(P, ST) do { const char* p_ = wb_ + (size_t)(ST)*32768; \
    _Pragma("unroll") for (int i_ = 0; i_ < 8; ++i_) \
      wf[P][i_] = *(const short8*)(p_ + i_*1024); } while(0)
#define XLOAD(P, ST) do { const char* p_ = xb_ + (size_t)(ST)*8192; \
    _Pragma("unroll") for (int i_ = 0; i_ < 8; ++i_) \
      xf[P][i_] = *(const short8*)(p_ + i_*1024); } while(0)

  WLOAD(0, 0);
  XLOAD(0, 0);
  #pragma unroll
  for (int st = 0; st < 8; ++st) {
    const int p = st & 1;
    if (st < 7) { WLOAD(p^1, st+1); XLOAD(p^1, st+1); }
    #pragma unroll
    for (int kk = 0; kk < 2; ++kk)
      #pragma unroll
      for (int mi = 0; mi < 4; ++mi)
        #pragma unroll
        for (int si = 0; si < 4; ++si)
          acc[mi][si] = MFMA(wf[p][mi*2+kk], xf[p][si*2+kk], acc[mi][si]);
  }
#undef WLOAD
#undef XLOAD

  float bias[4][4];
  #pragma unroll
  for (int mi = 0; mi < 4; ++mi)
    #pragma unroll
    for (int r = 0; r < 4; ++r) {
      int nch = w*64 + mi*16 + q*4 + r;
      bias[mi][r] = (nch < CN) ? bB[nch] : bV[nch - CN];
    }

  if (w < 2) {
    // B half: write raw bf16 rows + accumulate per-n sum of exp
    const size_t outb = (size_t)b * CN * HW;
    float psum[4][4] = {};
    #pragma unroll
    for (int mi = 0; mi < 4; ++mi)
      #pragma unroll
      for (int si = 0; si < 4; ++si) {
        int s = s0 + si*16 + l15;
        #pragma unroll
        for (int r = 0; r < 4; ++r) {
          int nch = w*64 + mi*16 + q*4 + r;
          __bf16 bv = (__bf16)(acc[mi][si][r] + bias[mi][r]);
          BVB[outb + (size_t)nch*HW + s] = bv;
          psum[mi][r] += __expf((float)bv);
        }
      }
    #pragma unroll
    for (int mi = 0; mi < 4; ++mi)
      #pragma unroll
      for (int r = 0; r < 4; ++r) {
        float v = psum[mi][r];
        v += __shfl_xor(v, 1); v += __shfl_xor(v, 2);
        v += __shfl_xor(v, 4); v += __shfl_xor(v, 8);
        if (l15 == 0) {
          int nch = w*64 + mi*16 + q*4 + r;
          atomicAdd(&bsum[b*CN + nch], v);
        }
      }
  } else {
    // V half: per-s max over its 128 V channels
    #pragma unroll
    for (int si = 0; si < 4; ++si) {
      float m = -1e30f;
      #pragma unroll
      for (int mi = 0; mi < 4; ++mi)
        #pragma unroll
        for (int r = 0; r < 4; ++r)
          m = fmaxf(m, acc[mi][si][r] + bias[mi][r]);
      m = fmaxf(m, __shfl_xor(m, 16));
      m = fmaxf(m, __shfl_xor(m, 32));
      if (q == 0) Vm[w-2][si*16 + l15] = m;
    }
  }
  wg_barrier();
  if (w >= 2) {
    #pragma unroll
    for (int si = 0; si < 4; ++si) {
      int idx = si*16 + l15;
      float ms = fmaxf(Vm[0][idx], Vm[1][idx]);
      float ssum = 0.f;
      #pragma unroll
      for (int mi = 0; mi < 4; ++mi)
        #pragma unroll
        for (int r = 0; r < 4; ++r) {
          float e = __expf(acc[mi][si][r] + bias[mi][r] - ms);
          acc[mi][si][r] = e;
          ssum += e;
        }
      ssum += __shfl_xor(ssum, 16);
      ssum += __shfl_xor(ssum, 32);
      if (q == 0) Vs[w-2][idx] = ssum;
    }
  }
  wg_barrier();
  if (w >= 2) {
    #pragma unroll
    for (int si = 0; si < 4; ++si) {
      int idx = si*16 + l15;
      float inv = 1.0f / (Vs[0][idx] + Vs[1][idx]);
      #pragma unroll
      for (int mi = 0; mi < 4; ++mi)
        #pragma unroll
        for (int r = 0; r < 4; ++r) {
          int j = (w-2)*64 + mi*16 + q*4 + r;
          T[idx*136 + j] = (__bf16)(acc[mi][si][r] * inv);
        }
    }
  }
  wg_barrier();
  __bf16* dst = attVT + ((size_t)b*HW + s0)*CN;
  #pragma unroll
  for (int k = 0; k < 4; ++k) {
    int chunk = tid + 256*k;
    int row = chunk >> 4, oct = chunk & 15;
    *(uint4*)&dst[(size_t)row*CN + oct*8] = *(uint4*)&T[row*136 + oct*8];
  }
}

// ---------------------------------------------------------------------------
// Kernel 2: H[b][c][n] += sum_s x[b][c][s] * (exp(BVB[n][s]) / bsum[n])
// BARRIER-FREE: 4 waves in 2x2 (64c x 64n) quadrants; fragments straight
// from global (x fp32 converted in regs, exp applied in regs), 14 half-steps
// of K=32 with one-half-step-ahead register prefetch.
// ---------------------------------------------------------------------------
__global__ __launch_bounds__(256) void h_gemm_kernel(
    const float* __restrict__ x, const __bf16* __restrict__ BVB,
    const float* __restrict__ bsum, float* __restrict__ H)
{
  const int c0 = blockIdx.x * 128, b = blockIdx.y, kc = blockIdx.z;
  const int tid = threadIdx.x, lane = tid & 63, w = tid >> 6;
  const int l15 = lane & 15, q = lane >> 4;
  const int wm = (w >> 1) * 64;   // c-half
  const int wn = (w & 1) * 64;    // n-half

  f32x4 acc[4][4] = {};   // [mi(c)][ni(n)]
  const float*  xa = x   + ((size_t)(b*CIN + c0 + wm + l15))*HW + q*8;
  const __bf16* bv = BVB + ((size_t)(b*CN  + wn + l15))*HW + q*8;

  float irow[4];
  #pragma unroll
  for (int ni = 0; ni < 4; ++ni)
    irow[ni] = 1.0f / bsum[b*CN + wn + ni*16 + l15];

  const int kbase = kc * 448;
  f32x4  pa[2][4][2];
  short8 pb[2][4];
#define HLOADA(P, K) do { _Pragma("unroll") for (int mi_ = 0; mi_ < 4; ++mi_) { \
    const float* s_ = xa + (size_t)mi_*16*HW + (K); \
    pa[P][mi_][0] = *(const f32x4*)s_; pa[P][mi_][1] = *(const f32x4*)(s_ + 4); } } while(0)
#define HLOADB(P, K) do { _Pragma("unroll") for (int ni_ = 0; ni_ < 4; ++ni_) \
    pb[P][ni_] = *(const short8*)(bv + (size_t)ni_*16*HW + (K)); } while(0)

  HLOADA(0, kbase);
  HLOADB(0, kbase);
  #pragma unroll
  for (int hs = 0; hs < 14; ++hs) {
    const int p = hs & 1;
    if (hs < 13) { HLOADA(p^1, kbase + (hs+1)*32); HLOADB(p^1, kbase + (hs+1)*32); }
    short8 af[4], bf[4];
    #pragma unroll
    for (int mi = 0; mi < 4; ++mi) af[mi] = cvt_frag(pa[p][mi][0], pa[p][mi][1]);
    #pragma unroll
    for (int ni = 0; ni < 4; ++ni) {
      const __bf16* vv = (const __bf16*)&pb[p][ni];
      union { __bf16 h[8]; short8 s; } u;
      #pragma unroll
      for (int j = 0; j < 8; ++j)
        u.h[j] = (__bf16)(__expf((float)vv[j]) * irow[ni]);
      bf[ni] = u.s;
    }
    #pragma unroll
    for (int mi = 0; mi < 4; ++mi)
      #pragma unroll
      for (int ni = 0; ni < 4; ++ni)
        acc[mi][ni] = MFMA(af[mi], bf[ni], acc[mi][ni]);
  }
#undef HLOADA
#undef HLOADB

  float* Hb = H + (size_t)b*CIN*CN;
  #pragma unroll
  for (int mi = 0; mi < 4; ++mi)
    #pragma unroll
    for (int ni = 0; ni < 4; ++ni)
      #pragma unroll
      for (int r = 0; r < 4; ++r) {
        int c = c0 + wm + mi*16 + q*4 + r;
        int n = wn + ni*16 + l15;
        atomicAdd(&Hb[c*CN + n], acc[mi][ni][r]);
      }
}

// ---------------------------------------------------------------------------
// Kernel 3: G[b] = wA @ H[b] + bA  (M=512 in 64-tiles, N=128, K=512) -> bf16
// ---------------------------------------------------------------------------
__global__ __launch_bounds__(256) void g_gemm_kernel(
    const float* __restrict__ wA, const float* __restrict__ bA,
    const float* __restrict__ H, __bf16* __restrict__ G)
{
  const int m0 = blockIdx.x * 64, b = blockIdx.y;
  const int tid = threadIdx.x, lane = tid & 63, w = tid >> 6;
  const int l15 = lane & 15, q = lane >> 4;

  __shared__ __attribute__((aligned(16))) __bf16 At[64*72];
  __shared__ __attribute__((aligned(16))) __bf16 Bt[128*72];
  f32x4 acc[4][2] = {};

  const float* Hb = H + (size_t)b*CIN*CN;
  const int colg = tid & 7, row0 = tid >> 3;
  const int nn = tid & 127, gh = tid >> 7;

  for (int k0 = 0; k0 < CIN; k0 += 64) {
    #pragma unroll
    for (int p = 0; p < 2; ++p) {
      int row = row0 + 32*p;
      cvt_store8(&At[row*72 + colg*8], wA + (size_t)(m0+row)*CIN + k0 + colg*8);
    }
    #pragma unroll
    for (int p = 0; p < 4; ++p) {
      int g = gh + 2*p;
      __attribute__((aligned(16))) __bf16 tmp[8];
      #pragma unroll
      for (int j = 0; j < 8; ++j)
        tmp[j] = (__bf16)Hb[(size_t)(k0 + g*8 + j)*CN + nn];
      *(uint4*)&Bt[nn*72 + g*8] = *(uint4*)tmp;
    }
    wg_barrier();
    #pragma unroll
    for (int kk = 0; kk < 2; ++kk) {
      short8 a[4], bb[2];
      #pragma unroll
      for (int mi = 0; mi < 4; ++mi)
        a[mi] = *(short8*)&At[(mi*16 + l15)*72 + kk*32 + q*8];
      #pragma unroll
      for (int ni = 0; ni < 2; ++ni)
        bb[ni] = *(short8*)&Bt[(w*32 + ni*16 + l15)*72 + kk*32 + q*8];
      #pragma unroll
      for (int mi = 0; mi < 4; ++mi)
        #pragma unroll
        for (int ni = 0; ni < 2; ++ni)
          acc[mi][ni] = MFMA(a[mi], bb[ni], acc[mi][ni]);
    }
    wg_barrier();
  }

  #pragma unroll
  for (int mi = 0; mi < 4; ++mi)
    #pragma unroll
    for (int ni = 0; ni < 2; ++ni)
      #pragma unroll
      for (int r = 0; r < 4; ++r) {
        int m = m0 + mi*16 + q*4 + r;
        int n = w*32 + ni*16 + l15;
        G[((size_t)b*CM + m)*CN + n] = (__bf16)(acc[mi][ni][r] + bA[m]);
      }
}

// ---------------------------------------------------------------------------
// Kernel 4: Z[b][m][s] = sum_n G[b][m][n] * attVT[b][s][n]  -> fp32 output
// BARRIER-FREE: both operands naturally n-contiguous; fragments straight
// from global (G L2-hot), kk-ahead prefetch of A fragments.
// ---------------------------------------------------------------------------
__global__ __launch_bounds__(256) void z_gemm_kernel(
    const __bf16* __restrict__ G, const __bf16* __restrict__ attVT,
    float* __restrict__ out)
{
  const int m0 = blockIdx.x * 128, s0 = blockIdx.y * 64, b = blockIdx.z;
  const int tid = threadIdx.x, lane = tid & 63, w = tid >> 6;
  const int l15 = lane & 15, q = lane >> 4;

  const __bf16* Ga = G + ((size_t)(b*CM + m0 + l15))*CN + q*8;
  const __bf16* Va = attVT + ((size_t)(b*HW + s0 + w*16 + l15))*CN + q*8;

  short8 bb[4];
  #pragma unroll
  for (int kk = 0; kk < 4; ++kk)
    bb[kk] = *(const short8*)(Va + kk*32);

  short8 a[2][8];
#define ZLOADA(P, KK) do { _Pragma("unroll") for (int mi_ = 0; mi_ < 8; ++mi_) \
    a[P][mi_] = *(const short8*)(Ga + (size_t)mi_*16*CN + (KK)*32); } while(0)

  ZLOADA(0, 0);
  f32x4 acc[8] = {};
  #pragma unroll
  for (int kk = 0; kk < 4; ++kk) {
    const int p = kk & 1;
    if (kk < 3) ZLOADA(p^1, kk+1);
    #pragma unroll
    for (int mi = 0; mi < 8; ++mi)
      acc[mi] = MFMA(a[p][mi], bb[kk], acc[mi]);
  }
#undef ZLOADA

  const int s = s0 + w*16 + l15;
  #pragma unroll
  for (int mi = 0; mi < 8; ++mi)
    #pragma unroll
    for (int r = 0; r < 4; ++r) {
      int m = m0 + mi*16 + q*4 + r;
      out[((size_t)b*CM + m)*HW + s] = acc[mi][r];
    }
}

// ---------------------------------------------------------------------------
extern "C" void kernel_launch(void* const* d_in, const int* in_sizes, int n_in,
                              void* d_out, int out_size, void* d_ws, size_t ws_size,
                              hipStream_t stream)
{
  (void)in_sizes; (void)n_in; (void)out_size; (void)ws_size;
  const float* x  = (const float*)d_in[0];
  const float* wA = (const float*)d_in[1];
  const float* bA = (const float*)d_in[2];
  const float* wB = (const float*)d_in[3];
  const float* bB = (const float*)d_in[4];
  const float* wV = (const float*)d_in[5];
  const float* bV = (const float*)d_in[6];
  float* out = (float*)d_out;

  char* ws = (char*)d_ws;
  const size_t szBVB   = (size_t)BATCH*CN*HW*2;       // 12,845,056
  const size_t szAttVT = (size_t)BATCH*HW*CN*2;       // 12,845,056
  const size_t szH     = (size_t)BATCH*CIN*CN*4;      //  4,194,304
  const size_t szBsum  = (size_t)BATCH*CN*4;          //      8,192
  const size_t szG     = (size_t)BATCH*CM*CN*2;       //  2,097,152
  const size_t szWimg  = (size_t)16384*16;            //    262,144
  // Ximg: 16 b x 49 s-tiles x 8 k-steps x 8192 B = 51,380,224

  char* p = ws;
  __bf16* BVB   = (__bf16*)p; p += szBVB;
  __bf16* attVT = (__bf16*)p; p += szAttVT;
  float*  H     = (float*)p;  p += szH;
  float*  bsum  = (float*)p;  p += szBsum;   // contiguous with H -> one memset
  __bf16* G     = (__bf16*)p; p += szG;
  __bf16* Wimg  = (__bf16*)p; p += szWimg;
  __bf16* Ximg  = (__bf16*)p;

  hipMemsetAsync(H, 0, szH + szBsum, stream);
  prep_w_kernel <<<dim3(64),       256, 0, stream>>>(wB, wV, Wimg);
  prep_x_kernel <<<dim3(49,8,16),  256, 0, stream>>>(x, Ximg);
  conv_bv_kernel<<<dim3(49,16),    256, 0, stream>>>(Ximg, Wimg, bB, bV, BVB, attVT, bsum);
  h_gemm_kernel <<<dim3(4,16,7),   256, 0, stream>>>(x, BVB, bsum, H);
  g_gemm_kernel <<<dim3(8,16),     256, 0, stream>>>(wA, bA, H, G);
  z_gemm_kernel <<<dim3(4,49,16),  256, 0, stream>>>(G, attVT, out);
}

// Round 6
// 288.606 us; speedup vs baseline: 1.2539x; 1.2539x over previous
//
#include <hip/hip_runtime.h>
#include <hip/hip_bf16.h>

#define BATCH 16
#define CIN   512
#define HW    3136
#define CM    512
#define CN    128

typedef short short8 __attribute__((ext_vector_type(8)));
typedef float f32x4  __attribute__((ext_vector_type(4)));

#define MFMA(a,b,c) __builtin_amdgcn_mfma_f32_16x16x32_bf16((a),(b),(c),0,0,0)

// convert 8 consecutive fp32 -> 8 bf16, store as one 16B chunk (LDS or global)
__device__ __forceinline__ void cvt_store8(__bf16* dst, const float* src) {
  const f32x4 a = *(const f32x4*)src;
  const f32x4 b = *(const f32x4*)(src + 4);
  __attribute__((aligned(16))) __bf16 t[8];
  t[0] = (__bf16)a[0]; t[1] = (__bf16)a[1]; t[2] = (__bf16)a[2]; t[3] = (__bf16)a[3];
  t[4] = (__bf16)b[0]; t[5] = (__bf16)b[1]; t[6] = (__bf16)b[2]; t[7] = (__bf16)b[3];
  *(uint4*)dst = *(uint4*)t;
}

// same, from two f32x4 by value (keeps sources in registers)
__device__ __forceinline__ void cvt_store8v(__bf16* dst, f32x4 a, f32x4 b) {
  __attribute__((aligned(16))) __bf16 t[8];
  t[0] = (__bf16)a[0]; t[1] = (__bf16)a[1]; t[2] = (__bf16)a[2]; t[3] = (__bf16)a[3];
  t[4] = (__bf16)b[0]; t[5] = (__bf16)b[1]; t[6] = (__bf16)b[2]; t[7] = (__bf16)b[3];
  *(uint4*)dst = *(uint4*)t;
}

// async 16B global->LDS copy (gfx950 global_load_lds_dwordx4)
__device__ __forceinline__ void load_lds16(const void* g, void* l) {
  __builtin_amdgcn_global_load_lds(
      (const __attribute__((address_space(1))) unsigned int*)g,
      (__attribute__((address_space(3))) unsigned int*)l, 16, 0, 0);
}

// ---------------------------------------------------------------------------
// Kernel 0: pre-convert (wB|wV) fp32 -> bf16 LDS tile images.
// 8 images (one per K-step of 64), each [256 rows][72 cols] bf16 = 36864 B,
// exactly the LDS byte layout conv_bv_kernel's fragment reads expect.
// ---------------------------------------------------------------------------
__global__ __launch_bounds__(256) void prep_w_kernel(
    const float* __restrict__ wB, const float* __restrict__ wV,
    __bf16* __restrict__ Wimg)
{
  const int k0  = blockIdx.x >> 2;                       // 0..7
  const int row = (blockIdx.x & 3) * 64 + (threadIdx.x >> 2);  // 0..255
  const int c0  = (threadIdx.x & 3) * 16;                // 0,16,32,48
  const float* src = (row < 128) ? (wB + (size_t)row * CIN)
                                 : (wV + (size_t)(row - 128) * CIN);
  src += k0 * 64 + c0;
  __bf16* dst = Wimg + (size_t)k0 * 18432 + row * 72 + c0;
  cvt_store8(dst, src);
  cvt_store8(dst + 8, src + 8);
}

// ---------------------------------------------------------------------------
// Kernel 1: conv (wB|wV) @ x + bias, x transposed IN-LDS (XOR-octet swizzle),
// fused V-softmax (transposed attVT out) and fused B-softmax row sums.
// W staged via async global_load_lds from pre-built bf16 images (L2/L3-hot);
// x staged via one-step-ahead register prefetch + swizzled pair-dword writes.
// (round-1 structure: best measured conv at 63.9 us)
// ---------------------------------------------------------------------------
__global__ __launch_bounds__(256) void conv_bv_kernel(
    const float* __restrict__ x,
    const __bf16* __restrict__ Wimg,
    const float* __restrict__ bB, const float* __restrict__ bV,
    __bf16* __restrict__ BVB, __bf16* __restrict__ attVT,
    float* __restrict__ bsum)
{
  const int s0  = blockIdx.x * 64;
  const int b   = blockIdx.y;
  const int tid = threadIdx.x;
  const int lane = tid & 63, w = tid >> 6;
  const int l15  = lane & 15, q = lane >> 4;

  __shared__ __attribute__((aligned(16))) char smem[46080]; // Wt 36864 | Xt 9216
  __bf16* Wt = (__bf16*)smem;            // [256][72]  (n-major, k-contig)
  __bf16* Xt = (__bf16*)(smem + 36864);  // [64][72]   (s-major, XOR-swizzled octets)
  __bf16* T  = (__bf16*)smem;            // [64][136]  epilogue alias
  __shared__ float Vm[2][64];
  __shared__ float Vs[2][64];

  f32x4 acc[4][4] = {};
  const float* xb = x + (size_t)b*CIN*HW + s0;
  const int colg = tid & 7;               // s-octet
  const int cl = 2*(tid >> 3);            // even c_local (pair cl, cl+1)
  const int xoff = ((cl >> 3) ^ colg)*8 + (cl & 7);

  // --- prologue: prefetch X tile for k0=0 into registers
  f32x4 pa0, pa1, pb0, pb1;
  {
    const float* r0 = xb + (size_t)cl*HW + colg*8;
    const float* r1 = r0 + HW;
    pa0 = *(const f32x4*)r0; pa1 = *(const f32x4*)(r0 + 4);
    pb0 = *(const f32x4*)r1; pb1 = *(const f32x4*)(r1 + 4);
  }

  for (int k0 = 0; k0 < CIN; k0 += 64) {
    // write Xt from prefetched registers (prev end-barrier guarantees Xt free)
    {
      float va[8] = {pa0[0],pa0[1],pa0[2],pa0[3],pa1[0],pa1[1],pa1[2],pa1[3]};
      float vb[8] = {pb0[0],pb0[1],pb0[2],pb0[3],pb1[0],pb1[1],pb1[2],pb1[3]};
      #pragma unroll
      for (int j = 0; j < 8; ++j) {
        int s = colg*8 + j;
        __attribute__((aligned(4))) __bf16 pairv[2] = { (__bf16)va[j], (__bf16)vb[j] };
        *(unsigned int*)&Xt[s*72 + xoff] = *(unsigned int*)pairv;
      }
    }
    // async-stage W image (36864 B = 9 x 16B chunks per thread, no VALU)
    {
      const char* wsrc = (const char*)Wimg + (size_t)(k0 >> 6)*36864 + tid*16;
      char* wdst = (char*)Wt + tid*16;
      #pragma unroll
      for (int i = 0; i < 9; ++i)
        load_lds16(wsrc + i*4096, wdst + i*4096);
    }
    // issue X prefetch for next step
    if (k0 + 64 < CIN) {
      const float* r0 = xb + (size_t)(k0 + 64 + cl)*HW + colg*8;
      const float* r1 = r0 + HW;
      pa0 = *(const f32x4*)r0; pa1 = *(const f32x4*)(r0 + 4);
      pb0 = *(const f32x4*)r1; pb1 = *(const f32x4*)(r1 + 4);
    }
    __syncthreads();
    #pragma unroll
    for (int kk = 0; kk < 2; ++kk) {
      short8 a[4], bb[4];
      #pragma unroll
      for (int mi = 0; mi < 4; ++mi)
        a[mi] = *(short8*)&Wt[(w*64 + mi*16 + l15)*72 + kk*32 + q*8];
      #pragma unroll
      for (int si = 0; si < 4; ++si) {
        int s = si*16 + l15;
        int oct = (kk*4 + q) ^ (si*2 + (l15 >> 3));
        bb[si] = *(short8*)&Xt[s*72 + oct*8];
      }
      #pragma unroll
      for (int mi = 0; mi < 4; ++mi)
        #pragma unroll
        for (int si = 0; si < 4; ++si)
          acc[mi][si] = MFMA(a[mi], bb[si], acc[mi][si]);
    }
    __syncthreads();
  }

  float bias[4][4];
  #pragma unroll
  for (int mi = 0; mi < 4; ++mi)
    #pragma unroll
    for (int r = 0; r < 4; ++r) {
      int nch = w*64 + mi*16 + q*4 + r;
      bias[mi][r] = (nch < CN) ? bB[nch] : bV[nch - CN];
    }

  if (w < 2) {
    // B half: write raw bf16 rows + accumulate per-n sum of exp
    const size_t outb = (size_t)b * CN * HW;
    float psum[4][4] = {};
    #pragma unroll
    for (int mi = 0; mi < 4; ++mi)
      #pragma unroll
      for (int si = 0; si < 4; ++si) {
        int s = s0 + si*16 + l15;
        #pragma unroll
        for (int r = 0; r < 4; ++r) {
          int nch = w*64 + mi*16 + q*4 + r;
          __bf16 bv = (__bf16)(acc[mi][si][r] + bias[mi][r]);
          BVB[outb + (size_t)nch*HW + s] = bv;
          psum[mi][r] += __expf((float)bv);
        }
      }
    #pragma unroll
    for (int mi = 0; mi < 4; ++mi)
      #pragma unroll
      for (int r = 0; r < 4; ++r) {
        float v = psum[mi][r];
        v += __shfl_xor(v, 1); v += __shfl_xor(v, 2);
        v += __shfl_xor(v, 4); v += __shfl_xor(v, 8);
        if (l15 == 0) {
          int nch = w*64 + mi*16 + q*4 + r;
          atomicAdd(&bsum[b*CN + nch], v);
        }
      }
  } else {
    // V half: per-s max over its 128 V channels
    #pragma unroll
    for (int si = 0; si < 4; ++si) {
      float m = -1e30f;
      #pragma unroll
      for (int mi = 0; mi < 4; ++mi)
        #pragma unroll
        for (int r = 0; r < 4; ++r)
          m = fmaxf(m, acc[mi][si][r] + bias[mi][r]);
      m = fmaxf(m, __shfl_xor(m, 16));
      m = fmaxf(m, __shfl_xor(m, 32));
      if (q == 0) Vm[w-2][si*16 + l15] = m;
    }
  }
  __syncthreads();
  if (w >= 2) {
    #pragma unroll
    for (int si = 0; si < 4; ++si) {
      int idx = si*16 + l15;
      float ms = fmaxf(Vm[0][idx], Vm[1][idx]);
      float ssum = 0.f;
      #pragma unroll
      for (int mi = 0; mi < 4; ++mi)
        #pragma unroll
        for (int r = 0; r < 4; ++r) {
          float e = __expf(acc[mi][si][r] + bias[mi][r] - ms);
          acc[mi][si][r] = e;
          ssum += e;
        }
      ssum += __shfl_xor(ssum, 16);
      ssum += __shfl_xor(ssum, 32);
      if (q == 0) Vs[w-2][idx] = ssum;
    }
  }
  __syncthreads();
  if (w >= 2) {
    #pragma unroll
    for (int si = 0; si < 4; ++si) {
      int idx = si*16 + l15;
      float inv = 1.0f / (Vs[0][idx] + Vs[1][idx]);
      #pragma unroll
      for (int mi = 0; mi < 4; ++mi)
        #pragma unroll
        for (int r = 0; r < 4; ++r) {
          int j = (w-2)*64 + mi*16 + q*4 + r;
          T[idx*136 + j] = (__bf16)(acc[mi][si][r] * inv);
        }
    }
  }
  __syncthreads();
  __bf16* dst = attVT + ((size_t)b*HW + s0)*CN;
  #pragma unroll
  for (int k = 0; k < 4; ++k) {
    int chunk = tid + 256*k;
    int row = chunk >> 4, oct = chunk & 15;
    *(uint4*)&dst[(size_t)row*CN + oct*8] = *(uint4*)&T[row*136 + oct*8];
  }
}

// ---------------------------------------------------------------------------
// Kernel 2: H[b][c][n] += sum_s x[b][c][s] * (exp(BVB[n][s]) / bsum[n])
// tile 128c x 128n, split-K=7, one-step-ahead register prefetch (round-1)
// ---------------------------------------------------------------------------
__global__ __launch_bounds__(256) void h_gemm_kernel(
    const float* __restrict__ x, const __bf16* __restrict__ BVB,
    const float* __restrict__ bsum, float* __restrict__ H)
{
  const int c0 = blockIdx.x * 128, b = blockIdx.y, kc = blockIdx.z;
  const int tid = threadIdx.x, lane = tid & 63, w = tid >> 6;
  const int l15 = lane & 15, q = lane >> 4;

  __shared__ __attribute__((aligned(16))) __bf16 At[128*72];  // x tile [c][s]
  __shared__ __attribute__((aligned(16))) __bf16 Bt[128*72];  // attB tile [n][s]
  f32x4 acc[8][2] = {};

  const float* xb = x + ((size_t)b*CIN + c0)*HW;
  const __bf16* ab = BVB + (size_t)b*CN*HW;
  const float* bsb = bsum + b*CN;
  const int colg = tid & 7, row0 = tid >> 3;

  float irow[4];
  #pragma unroll
  for (int p = 0; p < 4; ++p) irow[p] = 1.0f / bsb[row0 + 32*p];

  f32x4 px[4][2];
  uint4 pB[4];
#define HLOAD(K0) do { \
    _Pragma("unroll") \
    for (int p = 0; p < 4; ++p) { \
      const float* s_ = xb + (size_t)(row0 + 32*p)*HW + (K0) + colg*8; \
      px[p][0] = *(const f32x4*)s_; px[p][1] = *(const f32x4*)(s_ + 4); \
    } \
    _Pragma("unroll") \
    for (int p = 0; p < 4; ++p) \
      pB[p] = *(const uint4*)(ab + (size_t)(row0 + 32*p)*HW + (K0) + colg*8); \
  } while(0)

  const int kbase = kc * 448;
  HLOAD(kbase);

  for (int ki = 0; ki < 7; ++ki) {
    #pragma unroll
    for (int p = 0; p < 4; ++p)
      cvt_store8v(&At[(row0 + 32*p)*72 + colg*8], px[p][0], px[p][1]);
    #pragma unroll
    for (int p = 0; p < 4; ++p) {
      const __bf16* v = (const __bf16*)&pB[p];
      __attribute__((aligned(16))) __bf16 t[8];
      #pragma unroll
      for (int j = 0; j < 8; ++j)
        t[j] = (__bf16)(__expf((float)v[j]) * irow[p]);
      *(uint4*)&Bt[(row0 + 32*p)*72 + colg*8] = *(uint4*)t;
    }
    if (ki < 6) HLOAD(kbase + (ki + 1)*64);
    __syncthreads();
    #pragma unroll
    for (int kk = 0; kk < 2; ++kk) {
      short8 a[8], bb[2];
      #pragma unroll
      for (int mi = 0; mi < 8; ++mi)
        a[mi] = *(short8*)&At[(mi*16 + l15)*72 + kk*32 + q*8];
      #pragma unroll
      for (int ni = 0; ni < 2; ++ni)
        bb[ni] = *(short8*)&Bt[(w*32 + ni*16 + l15)*72 + kk*32 + q*8];
      #pragma unroll
      for (int mi = 0; mi < 8; ++mi)
        #pragma unroll
        for (int ni = 0; ni < 2; ++ni)
          acc[mi][ni] = MFMA(a[mi], bb[ni], acc[mi][ni]);
    }
    __syncthreads();
  }
#undef HLOAD

  float* Hb = H + (size_t)b*CIN*CN;
  #pragma unroll
  for (int mi = 0; mi < 8; ++mi)
    #pragma unroll
    for (int ni = 0; ni < 2; ++ni)
      #pragma unroll
      for (int r = 0; r < 4; ++r) {
        int c = c0 + mi*16 + q*4 + r;
        int n = w*32 + ni*16 + l15;
        atomicAdd(&Hb[c*CN + n], acc[mi][ni][r]);
      }
}

// ---------------------------------------------------------------------------
// Kernel 3: G[b] = wA @ H[b] + bA  (M=512 in 64-tiles, N=128, K=512) -> bf16
// ---------------------------------------------------------------------------
__global__ __launch_bounds__(256) void g_gemm_kernel(
    const float* __restrict__ wA, const float* __restrict__ bA,
    const float* __restrict__ H, __bf16* __restrict__ G)
{
  const int m0 = blockIdx.x * 64, b = blockIdx.y;
  const int tid = threadIdx.x, lane = tid & 63, w = tid >> 6;
  const int l15 = lane & 15, q = lane >> 4;

  __shared__ __attribute__((aligned(16))) __bf16 At[64*72];
  __shared__ __attribute__((aligned(16))) __bf16 Bt[128*72];
  f32x4 acc[4][2] = {};

  const float* Hb = H + (size_t)b*CIN*CN;
  const int colg = tid & 7, row0 = tid >> 3;
  const int nn = tid & 127, gh = tid >> 7;

  for (int k0 = 0; k0 < CIN; k0 += 64) {
    #pragma unroll
    for (int p = 0; p < 2; ++p) {
      int row = row0 + 32*p;
      cvt_store8(&At[row*72 + colg*8], wA + (size_t)(m0+row)*CIN + k0 + colg*8);
    }
    #pragma unroll
    for (int p = 0; p < 4; ++p) {
      int g = gh + 2*p;
      __attribute__((aligned(16))) __bf16 tmp[8];
      #pragma unroll
      for (int j = 0; j < 8; ++j)
        tmp[j] = (__bf16)Hb[(size_t)(k0 + g*8 + j)*CN + nn];
      *(uint4*)&Bt[nn*72 + g*8] = *(uint4*)tmp;
    }
    __syncthreads();
    #pragma unroll
    for (int kk = 0; kk < 2; ++kk) {
      short8 a[4], bb[2];
      #pragma unroll
      for (int mi = 0; mi < 4; ++mi)
        a[mi] = *(short8*)&At[(mi*16 + l15)*72 + kk*32 + q*8];
      #pragma unroll
      for (int ni = 0; ni < 2; ++ni)
        bb[ni] = *(short8*)&Bt[(w*32 + ni*16 + l15)*72 + kk*32 + q*8];
      #pragma unroll
      for (int mi = 0; mi < 4; ++mi)
        #pragma unroll
        for (int ni = 0; ni < 2; ++ni)
          acc[mi][ni] = MFMA(a[mi], bb[ni], acc[mi][ni]);
    }
    __syncthreads();
  }

  #pragma unroll
  for (int mi = 0; mi < 4; ++mi)
    #pragma unroll
    for (int ni = 0; ni < 2; ++ni)
      #pragma unroll
      for (int r = 0; r < 4; ++r) {
        int m = m0 + mi*16 + q*4 + r;
        int n = w*32 + ni*16 + l15;
        G[((size_t)b*CM + m)*CN + n] = (__bf16)(acc[mi][ni][r] + bA[m]);
      }
}

// ---------------------------------------------------------------------------
// Kernel 4: Z[b][m][s] = sum_n G[b][m][n] * attVT[b][s][n]  -> fp32 output
// Fat blocks: 256m x 64s per block (grid 2x49x16), 64 MFMA/wave with a
// double-buffered kk-loop; fragments straight from global (G L2-hot,
// attVT re-read only 2x). No LDS, no barriers.
// ---------------------------------------------------------------------------
__global__ __launch_bounds__(256) void z_gemm_kernel(
    const __bf16* __restrict__ G, const __bf16* __restrict__ attVT,
    float* __restrict__ out)
{
  const int s0 = blockIdx.y * 64, b = blockIdx.z;
  const int tid = threadIdx.x, lane = tid & 63, w = tid >> 6;
  const int l15 = lane & 15, q = lane >> 4;
  const int m0 = blockIdx.x * 256 + w * 64;   // wave owns 64 m-rows

  const __bf16* Ga = G + ((size_t)(b*CM + m0 + l15))*CN + q*8;
  const __bf16* Va = attVT + ((size_t)(b*HW + s0 + l15))*CN + q*8;

  f32x4 acc[4][4] = {};   // [mi][si]
  short8 a[2][4], bb[2][4];
#define ZLOAD(P, KK) do { \
    _Pragma("unroll") for (int mi_ = 0; mi_ < 4; ++mi_) \
      a[P][mi_] = *(const short8*)(Ga + (size_t)mi_*16*CN + (KK)*32); \
    _Pragma("unroll") for (int si_ = 0; si_ < 4; ++si_) \
      bb[P][si_] = *(const short8*)(Va + (size_t)si_*16*CN + (KK)*32); } while(0)

  ZLOAD(0, 0);
  #pragma unroll
  for (int kk = 0; kk < 4; ++kk) {
    const int p = kk & 1;
    if (kk < 3) ZLOAD(p^1, kk+1);
    #pragma unroll
    for (int mi = 0; mi < 4; ++mi)
      #pragma unroll
      for (int si = 0; si < 4; ++si)
        acc[mi][si] = MFMA(a[p][mi], bb[p][si], acc[mi][si]);
  }
#undef ZLOAD

  #pragma unroll
  for (int mi = 0; mi < 4; ++mi)
    #pragma unroll
    for (int si = 0; si < 4; ++si) {
      const int s = s0 + si*16 + l15;
      #pragma unroll
      for (int r = 0; r < 4; ++r) {
        int m = m0 + mi*16 + q*4 + r;
        out[((size_t)b*CM + m)*HW + s] = acc[mi][si][r];
      }
    }
}

// ---------------------------------------------------------------------------
extern "C" void kernel_launch(void* const* d_in, const int* in_sizes, int n_in,
                              void* d_out, int out_size, void* d_ws, size_t ws_size,
                              hipStream_t stream)
{
  (void)in_sizes; (void)n_in; (void)out_size; (void)ws_size;
  const float* x  = (const float*)d_in[0];
  const float* wA = (const float*)d_in[1];
  const float* bA = (const float*)d_in[2];
  const float* wB = (const float*)d_in[3];
  const float* bB = (const float*)d_in[4];
  const float* wV = (const float*)d_in[5];
  const float* bV = (const float*)d_in[6];
  float* out = (float*)d_out;

  char* ws = (char*)d_ws;
  const size_t szBVB   = (size_t)BATCH*CN*HW*2;     // 12,845,056
  const size_t szAttVT = (size_t)BATCH*HW*CN*2;     // 12,845,056
  const size_t szH     = (size_t)BATCH*CIN*CN*4;    //  4,194,304
  const size_t szBsum  = (size_t)BATCH*CN*4;        //      8,192
  const size_t szG     = (size_t)BATCH*CM*CN*2;     //  2,097,152

  char* p = ws;
  __bf16* BVB   = (__bf16*)p; p += szBVB;
  __bf16* attVT = (__bf16*)p; p += szAttVT;
  float*  H     = (float*)p;  p += szH;
  float*  bsum  = (float*)p;  p += szBsum;   // contiguous with H -> one memset
  __bf16* G     = (__bf16*)p; p += szG;
  __bf16* Wimg  = (__bf16*)p;                // 8 x 36864 B = 294,912

  hipMemsetAsync(H, 0, szH + szBsum, stream);
  prep_w_kernel <<<dim3(32),      256, 0, stream>>>(wB, wV, Wimg);
  conv_bv_kernel<<<dim3(49,16),   256, 0, stream>>>(x, Wimg, bB, bV, BVB, attVT, bsum);
  h_gemm_kernel <<<dim3(4,16,7),  256, 0, stream>>>(x, BVB, bsum, H);
  g_gemm_kernel <<<dim3(8,16),    256, 0, stream>>>(wA, bA, H, G);
  z_gemm_kernel <<<dim3(2,49,16), 256, 0, stream>>>(G, attVT, out);
}

// Round 7
// 286.266 us; speedup vs baseline: 1.2642x; 1.0082x over previous
//
#include <hip/hip_runtime.h>
#include <hip/hip_bf16.h>

#define BATCH 16
#define CIN   512
#define HW    3136
#define CM    512
#define CN    128

typedef short short8 __attribute__((ext_vector_type(8)));
typedef float f32x4  __attribute__((ext_vector_type(4)));

#define MFMA(a,b,c) __builtin_amdgcn_mfma_f32_16x16x32_bf16((a),(b),(c),0,0,0)

// convert 8 consecutive fp32 -> 8 bf16, store as one 16B chunk (LDS or global)
__device__ __forceinline__ void cvt_store8(__bf16* dst, const float* src) {
  const f32x4 a = *(const f32x4*)src;
  const f32x4 b = *(const f32x4*)(src + 4);
  __attribute__((aligned(16))) __bf16 t[8];
  t[0] = (__bf16)a[0]; t[1] = (__bf16)a[1]; t[2] = (__bf16)a[2]; t[3] = (__bf16)a[3];
  t[4] = (__bf16)b[0]; t[5] = (__bf16)b[1]; t[6] = (__bf16)b[2]; t[7] = (__bf16)b[3];
  *(uint4*)dst = *(uint4*)t;
}

// same, from two f32x4 by value (keeps sources in registers)
__device__ __forceinline__ void cvt_store8v(__bf16* dst, f32x4 a, f32x4 b) {
  __attribute__((aligned(16))) __bf16 t[8];
  t[0] = (__bf16)a[0]; t[1] = (__bf16)a[1]; t[2] = (__bf16)a[2]; t[3] = (__bf16)a[3];
  t[4] = (__bf16)b[0]; t[5] = (__bf16)b[1]; t[6] = (__bf16)b[2]; t[7] = (__bf16)b[3];
  *(uint4*)dst = *(uint4*)t;
}

// async 16B global->LDS copy (gfx950 global_load_lds_dwordx4)
__device__ __forceinline__ void load_lds16(const void* g, void* l) {
  __builtin_amdgcn_global_load_lds(
      (const __attribute__((address_space(1))) unsigned int*)g,
      (__attribute__((address_space(3))) unsigned int*)l, 16, 0, 0);
}

// ---------------------------------------------------------------------------
// Kernel 0: pre-convert (wB|wV) fp32 -> bf16 LDS tile images.
// 8 images (one per K-step of 64), each [256 rows][72 cols] bf16 = 36864 B,
// exactly the LDS byte layout conv_bv_kernel's fragment reads expect.
// ---------------------------------------------------------------------------
__global__ __launch_bounds__(256) void prep_w_kernel(
    const float* __restrict__ wB, const float* __restrict__ wV,
    __bf16* __restrict__ Wimg)
{
  const int k0  = blockIdx.x >> 2;                       // 0..7
  const int row = (blockIdx.x & 3) * 64 + (threadIdx.x >> 2);  // 0..255
  const int c0  = (threadIdx.x & 3) * 16;                // 0,16,32,48
  const float* src = (row < 128) ? (wB + (size_t)row * CIN)
                                 : (wV + (size_t)(row - 128) * CIN);
  src += k0 * 64 + c0;
  __bf16* dst = Wimg + (size_t)k0 * 18432 + row * 72 + c0;
  cvt_store8(dst, src);
  cvt_store8(dst + 8, src + 8);
}

// ---------------------------------------------------------------------------
// Kernel 1: conv (wB|wV) @ x + bias, x transposed IN-LDS (XOR-octet swizzle),
// fused V-softmax (transposed attVT out) and fused B-softmax row sums.
// B-half now stores expB[n][s] = (bf16)exp(conv_out) -- the exp was already
// computed for the bsum reduction; h_gemm then stages it as a raw copy and
// the 1/bsum normalization moves to g_gemm (exact: scaling is per-n).
// ---------------------------------------------------------------------------
__global__ __launch_bounds__(256) void conv_bv_kernel(
    const float* __restrict__ x,
    const __bf16* __restrict__ Wimg,
    const float* __restrict__ bB, const float* __restrict__ bV,
    __bf16* __restrict__ expB, __bf16* __restrict__ attVT,
    float* __restrict__ bsum)
{
  const int s0  = blockIdx.x * 64;
  const int b   = blockIdx.y;
  const int tid = threadIdx.x;
  const int lane = tid & 63, w = tid >> 6;
  const int l15  = lane & 15, q = lane >> 4;

  __shared__ __attribute__((aligned(16))) char smem[46080]; // Wt 36864 | Xt 9216
  __bf16* Wt = (__bf16*)smem;            // [256][72]  (n-major, k-contig)
  __bf16* Xt = (__bf16*)(smem + 36864);  // [64][72]   (s-major, XOR-swizzled octets)
  __bf16* T  = (__bf16*)smem;            // [64][136]  epilogue alias
  __shared__ float Vm[2][64];
  __shared__ float Vs[2][64];

  f32x4 acc[4][4] = {};
  const float* xb = x + (size_t)b*CIN*HW + s0;
  const int colg = tid & 7;               // s-octet
  const int cl = 2*(tid >> 3);            // even c_local (pair cl, cl+1)
  const int xoff = ((cl >> 3) ^ colg)*8 + (cl & 7);

  // --- prologue: prefetch X tile for k0=0 into registers
  f32x4 pa0, pa1, pb0, pb1;
  {
    const float* r0 = xb + (size_t)cl*HW + colg*8;
    const float* r1 = r0 + HW;
    pa0 = *(const f32x4*)r0; pa1 = *(const f32x4*)(r0 + 4);
    pb0 = *(const f32x4*)r1; pb1 = *(const f32x4*)(r1 + 4);
  }

  for (int k0 = 0; k0 < CIN; k0 += 64) {
    // write Xt from prefetched registers (prev end-barrier guarantees Xt free)
    {
      float va[8] = {pa0[0],pa0[1],pa0[2],pa0[3],pa1[0],pa1[1],pa1[2],pa1[3]};
      float vb[8] = {pb0[0],pb0[1],pb0[2],pb0[3],pb1[0],pb1[1],pb1[2],pb1[3]};
      #pragma unroll
      for (int j = 0; j < 8; ++j) {
        int s = colg*8 + j;
        __attribute__((aligned(4))) __bf16 pairv[2] = { (__bf16)va[j], (__bf16)vb[j] };
        *(unsigned int*)&Xt[s*72 + xoff] = *(unsigned int*)pairv;
      }
    }
    // async-stage W image (36864 B = 9 x 16B chunks per thread, no VALU)
    {
      const char* wsrc = (const char*)Wimg + (size_t)(k0 >> 6)*36864 + tid*16;
      char* wdst = (char*)Wt + tid*16;
      #pragma unroll
      for (int i = 0; i < 9; ++i)
        load_lds16(wsrc + i*4096, wdst + i*4096);
    }
    // issue X prefetch for next step
    if (k0 + 64 < CIN) {
      const float* r0 = xb + (size_t)(k0 + 64 + cl)*HW + colg*8;
      const float* r1 = r0 + HW;
      pa0 = *(const f32x4*)r0; pa1 = *(const f32x4*)(r0 + 4);
      pb0 = *(const f32x4*)r1; pb1 = *(const f32x4*)(r1 + 4);
    }
    __syncthreads();
    #pragma unroll
    for (int kk = 0; kk < 2; ++kk) {
      short8 a[4], bb[4];
      #pragma unroll
      for (int mi = 0; mi < 4; ++mi)
        a[mi] = *(short8*)&Wt[(w*64 + mi*16 + l15)*72 + kk*32 + q*8];
      #pragma unroll
      for (int si = 0; si < 4; ++si) {
        int s = si*16 + l15;
        int oct = (kk*4 + q) ^ (si*2 + (l15 >> 3));
        bb[si] = *(short8*)&Xt[s*72 + oct*8];
      }
      #pragma unroll
      for (int mi = 0; mi < 4; ++mi)
        #pragma unroll
        for (int si = 0; si < 4; ++si)
          acc[mi][si] = MFMA(a[mi], bb[si], acc[mi][si]);
    }
    __syncthreads();
  }

  float bias[4][4];
  #pragma unroll
  for (int mi = 0; mi < 4; ++mi)
    #pragma unroll
    for (int r = 0; r < 4; ++r) {
      int nch = w*64 + mi*16 + q*4 + r;
      bias[mi][r] = (nch < CN) ? bB[nch] : bV[nch - CN];
    }

  if (w < 2) {
    // B half: write exp(bf16 conv out) rows + accumulate per-n sum of exp
    const size_t outb = (size_t)b * CN * HW;
    float psum[4][4] = {};
    #pragma unroll
    for (int mi = 0; mi < 4; ++mi)
      #pragma unroll
      for (int si = 0; si < 4; ++si) {
        int s = s0 + si*16 + l15;
        #pragma unroll
        for (int r = 0; r < 4; ++r) {
          int nch = w*64 + mi*16 + q*4 + r;
          __bf16 bv = (__bf16)(acc[mi][si][r] + bias[mi][r]);
          float e = __expf((float)bv);
          expB[outb + (size_t)nch*HW + s] = (__bf16)e;
          psum[mi][r] += e;
        }
      }
    #pragma unroll
    for (int mi = 0; mi < 4; ++mi)
      #pragma unroll
      for (int r = 0; r < 4; ++r) {
        float v = psum[mi][r];
        v += __shfl_xor(v, 1); v += __shfl_xor(v, 2);
        v += __shfl_xor(v, 4); v += __shfl_xor(v, 8);
        if (l15 == 0) {
          int nch = w*64 + mi*16 + q*4 + r;
          atomicAdd(&bsum[b*CN + nch], v);
        }
      }
  } else {
    // V half: per-s max over its 128 V channels
    #pragma unroll
    for (int si = 0; si < 4; ++si) {
      float m = -1e30f;
      #pragma unroll
      for (int mi = 0; mi < 4; ++mi)
        #pragma unroll
        for (int r = 0; r < 4; ++r)
          m = fmaxf(m, acc[mi][si][r] + bias[mi][r]);
      m = fmaxf(m, __shfl_xor(m, 16));
      m = fmaxf(m, __shfl_xor(m, 32));
      if (q == 0) Vm[w-2][si*16 + l15] = m;
    }
  }
  __syncthreads();
  if (w >= 2) {
    #pragma unroll
    for (int si = 0; si < 4; ++si) {
      int idx = si*16 + l15;
      float ms = fmaxf(Vm[0][idx], Vm[1][idx]);
      float ssum = 0.f;
      #pragma unroll
      for (int mi = 0; mi < 4; ++mi)
        #pragma unroll
        for (int r = 0; r < 4; ++r) {
          float e = __expf(acc[mi][si][r] + bias[mi][r] - ms);
          acc[mi][si][r] = e;
          ssum += e;
        }
      ssum += __shfl_xor(ssum, 16);
      ssum += __shfl_xor(ssum, 32);
      if (q == 0) Vs[w-2][idx] = ssum;
    }
  }
  __syncthreads();
  if (w >= 2) {
    #pragma unroll
    for (int si = 0; si < 4; ++si) {
      int idx = si*16 + l15;
      float inv = 1.0f / (Vs[0][idx] + Vs[1][idx]);
      #pragma unroll
      for (int mi = 0; mi < 4; ++mi)
        #pragma unroll
        for (int r = 0; r < 4; ++r) {
          int j = (w-2)*64 + mi*16 + q*4 + r;
          T[idx*136 + j] = (__bf16)(acc[mi][si][r] * inv);
        }
    }
  }
  __syncthreads();
  __bf16* dst = attVT + ((size_t)b*HW + s0)*CN;
  #pragma unroll
  for (int k = 0; k < 4; ++k) {
    int chunk = tid + 256*k;
    int row = chunk >> 4, oct = chunk & 15;
    *(uint4*)&dst[(size_t)row*CN + oct*8] = *(uint4*)&T[row*136 + oct*8];
  }
}

// ---------------------------------------------------------------------------
// Kernel 2: Hraw[b][c][n] += sum_s x[b][c][s] * expB[n][s]
// tile 128c x 128n, split-K=7, one-step-ahead register prefetch.
// Bt staging is now a PURE COPY (exp moved to conv, 1/bsum moved to g).
// ---------------------------------------------------------------------------
__global__ __launch_bounds__(256) void h_gemm_kernel(
    const float* __restrict__ x, const __bf16* __restrict__ expB,
    float* __restrict__ H)
{
  const int c0 = blockIdx.x * 128, b = blockIdx.y, kc = blockIdx.z;
  const int tid = threadIdx.x, lane = tid & 63, w = tid >> 6;
  const int l15 = lane & 15, q = lane >> 4;

  __shared__ __attribute__((aligned(16))) __bf16 At[128*72];  // x tile [c][s]
  __shared__ __attribute__((aligned(16))) __bf16 Bt[128*72];  // expB tile [n][s]
  f32x4 acc[8][2] = {};

  const float* xb = x + ((size_t)b*CIN + c0)*HW;
  const __bf16* ab = expB + (size_t)b*CN*HW;
  const int colg = tid & 7, row0 = tid >> 3;

  f32x4 px[4][2];
  uint4 pB[4];
#define HLOAD(K0) do { \
    _Pragma("unroll") \
    for (int p = 0; p < 4; ++p) { \
      const float* s_ = xb + (size_t)(row0 + 32*p)*HW + (K0) + colg*8; \
      px[p][0] = *(const f32x4*)s_; px[p][1] = *(const f32x4*)(s_ + 4); \
    } \
    _Pragma("unroll") \
    for (int p = 0; p < 4; ++p) \
      pB[p] = *(const uint4*)(ab + (size_t)(row0 + 32*p)*HW + (K0) + colg*8); \
  } while(0)

  const int kbase = kc * 448;
  HLOAD(kbase);

  for (int ki = 0; ki < 7; ++ki) {
    #pragma unroll
    for (int p = 0; p < 4; ++p)
      cvt_store8v(&At[(row0 + 32*p)*72 + colg*8], px[p][0], px[p][1]);
    #pragma unroll
    for (int p = 0; p < 4; ++p)
      *(uint4*)&Bt[(row0 + 32*p)*72 + colg*8] = pB[p];
    if (ki < 6) HLOAD(kbase + (ki + 1)*64);
    __syncthreads();
    #pragma unroll
    for (int kk = 0; kk < 2; ++kk) {
      short8 a[8], bb[2];
      #pragma unroll
      for (int mi = 0; mi < 8; ++mi)
        a[mi] = *(short8*)&At[(mi*16 + l15)*72 + kk*32 + q*8];
      #pragma unroll
      for (int ni = 0; ni < 2; ++ni)
        bb[ni] = *(short8*)&Bt[(w*32 + ni*16 + l15)*72 + kk*32 + q*8];
      #pragma unroll
      for (int mi = 0; mi < 8; ++mi)
        #pragma unroll
        for (int ni = 0; ni < 2; ++ni)
          acc[mi][ni] = MFMA(a[mi], bb[ni], acc[mi][ni]);
    }
    __syncthreads();
  }
#undef HLOAD

  float* Hb = H + (size_t)b*CIN*CN;
  #pragma unroll
  for (int mi = 0; mi < 8; ++mi)
    #pragma unroll
    for (int ni = 0; ni < 2; ++ni)
      #pragma unroll
      for (int r = 0; r < 4; ++r) {
        int c = c0 + mi*16 + q*4 + r;
        int n = w*32 + ni*16 + l15;
        atomicAdd(&Hb[c*CN + n], acc[mi][ni][r]);
      }
}

// ---------------------------------------------------------------------------
// Kernel 3: G[b] = wA @ (Hraw[b] * diag(1/bsum)) + bA -> bf16
// 1/bsum applied per-n at Bt staging (exact: H column n scales uniformly).
// ---------------------------------------------------------------------------
__global__ __launch_bounds__(256) void g_gemm_kernel(
    const float* __restrict__ wA, const float* __restrict__ bA,
    const float* __restrict__ H, const float* __restrict__ bsum,
    __bf16* __restrict__ G)
{
  const int m0 = blockIdx.x * 64, b = blockIdx.y;
  const int tid = threadIdx.x, lane = tid & 63, w = tid >> 6;
  const int l15 = lane & 15, q = lane >> 4;

  __shared__ __attribute__((aligned(16))) __bf16 At[64*72];
  __shared__ __attribute__((aligned(16))) __bf16 Bt[128*72];
  f32x4 acc[4][2] = {};

  const float* Hb = H + (size_t)b*CIN*CN;
  const int colg = tid & 7, row0 = tid >> 3;
  const int nn = tid & 127, gh = tid >> 7;
  const float inv = 1.0f / bsum[b*CN + nn];

  for (int k0 = 0; k0 < CIN; k0 += 64) {
    #pragma unroll
    for (int p = 0; p < 2; ++p) {
      int row = row0 + 32*p;
      cvt_store8(&At[row*72 + colg*8], wA + (size_t)(m0+row)*CIN + k0 + colg*8);
    }
    #pragma unroll
    for (int p = 0; p < 4; ++p) {
      int g = gh + 2*p;
      __attribute__((aligned(16))) __bf16 tmp[8];
      #pragma unroll
      for (int j = 0; j < 8; ++j)
        tmp[j] = (__bf16)(Hb[(size_t)(k0 + g*8 + j)*CN + nn] * inv);
      *(uint4*)&Bt[nn*72 + g*8] = *(uint4*)tmp;
    }
    __syncthreads();
    #pragma unroll
    for (int kk = 0; kk < 2; ++kk) {
      short8 a[4], bb[2];
      #pragma unroll
      for (int mi = 0; mi < 4; ++mi)
        a[mi] = *(short8*)&At[(mi*16 + l15)*72 + kk*32 + q*8];
      #pragma unroll
      for (int ni = 0; ni < 2; ++ni)
        bb[ni] = *(short8*)&Bt[(w*32 + ni*16 + l15)*72 + kk*32 + q*8];
      #pragma unroll
      for (int mi = 0; mi < 4; ++mi)
        #pragma unroll
        for (int ni = 0; ni < 2; ++ni)
          acc[mi][ni] = MFMA(a[mi], bb[ni], acc[mi][ni]);
    }
    __syncthreads();
  }

  #pragma unroll
  for (int mi = 0; mi < 4; ++mi)
    #pragma unroll
    for (int ni = 0; ni < 2; ++ni)
      #pragma unroll
      for (int r = 0; r < 4; ++r) {
        int m = m0 + mi*16 + q*4 + r;
        int n = w*32 + ni*16 + l15;
        G[((size_t)b*CM + m)*CN + n] = (__bf16)(acc[mi][ni][r] + bA[m]);
      }
}

// ---------------------------------------------------------------------------
// Kernel 4: Z[b][m][s] = sum_n G[b][m][n] * attVT[b][s][n]  -> fp32 output
// (round-0/1 LDS version: stage both tiles, one barrier, 32 MFMA/wave --
//  measured-best z configuration)
// ---------------------------------------------------------------------------
__global__ __launch_bounds__(256) void z_gemm_kernel(
    const __bf16* __restrict__ G, const __bf16* __restrict__ attVT,
    float* __restrict__ out)
{
  const int m0 = blockIdx.x * 128, s0 = blockIdx.y * 64, b = blockIdx.z;
  const int tid = threadIdx.x, lane = tid & 63, w = tid >> 6;
  const int l15 = lane & 15, q = lane >> 4;

  __shared__ __attribute__((aligned(16))) __bf16 At[128*136];
  __shared__ __attribute__((aligned(16))) __bf16 Bt[64*136];

  const __bf16* Gb = G + ((size_t)b*CM + m0)*CN;
  const __bf16* Vb = attVT + ((size_t)b*HW + s0)*CN;
  const int g = tid & 15, r0 = tid >> 4;
  #pragma unroll
  for (int p = 0; p < 8; ++p) {
    int row = r0 + 16*p;
    *(uint4*)&At[row*136 + g*8] = *(const uint4*)(Gb + (size_t)row*CN + g*8);
  }
  #pragma unroll
  for (int p = 0; p < 4; ++p) {
    int row = r0 + 16*p;
    *(uint4*)&Bt[row*136 + g*8] = *(const uint4*)(Vb + (size_t)row*CN + g*8);
  }
  __syncthreads();

  f32x4 acc[8] = {};
  #pragma unroll
  for (int kk = 0; kk < 4; ++kk) {
    short8 bb = *(short8*)&Bt[(w*16 + l15)*136 + kk*32 + q*8];
    #pragma unroll
    for (int mi = 0; mi < 8; ++mi) {
      short8 a = *(short8*)&At[(mi*16 + l15)*136 + kk*32 + q*8];
      acc[mi] = MFMA(a, bb, acc[mi]);
    }
  }

  const int s = s0 + w*16 + l15;
  #pragma unroll
  for (int mi = 0; mi < 8; ++mi)
    #pragma unroll
    for (int r = 0; r < 4; ++r) {
      int m = m0 + mi*16 + q*4 + r;
      out[((size_t)b*CM + m)*HW + s] = acc[mi][r];
    }
}

// ---------------------------------------------------------------------------
extern "C" void kernel_launch(void* const* d_in, const int* in_sizes, int n_in,
                              void* d_out, int out_size, void* d_ws, size_t ws_size,
                              hipStream_t stream)
{
  (void)in_sizes; (void)n_in; (void)out_size; (void)ws_size;
  const float* x  = (const float*)d_in[0];
  const float* wA = (const float*)d_in[1];
  const float* bA = (const float*)d_in[2];
  const float* wB = (const float*)d_in[3];
  const float* bB = (const float*)d_in[4];
  const float* wV = (const float*)d_in[5];
  const float* bV = (const float*)d_in[6];
  float* out = (float*)d_out;

  char* ws = (char*)d_ws;
  const size_t szBVB   = (size_t)BATCH*CN*HW*2;     // 12,845,056  (expB)
  const size_t szAttVT = (size_t)BATCH*HW*CN*2;     // 12,845,056
  const size_t szH     = (size_t)BATCH*CIN*CN*4;    //  4,194,304
  const size_t szBsum  = (size_t)BATCH*CN*4;        //      8,192
  const size_t szG     = (size_t)BATCH*CM*CN*2;     //  2,097,152

  char* p = ws;
  __bf16* expB  = (__bf16*)p; p += szBVB;
  __bf16* attVT = (__bf16*)p; p += szAttVT;
  float*  H     = (float*)p;  p += szH;
  float*  bsum  = (float*)p;  p += szBsum;   // contiguous with H -> one memset
  __bf16* G     = (__bf16*)p; p += szG;
  __bf16* Wimg  = (__bf16*)p;                // 8 x 36864 B = 294,912

  hipMemsetAsync(H, 0, szH + szBsum, stream);
  prep_w_kernel <<<dim3(32),      256, 0, stream>>>(wB, wV, Wimg);
  conv_bv_kernel<<<dim3(49,16),   256, 0, stream>>>(x, Wimg, bB, bV, expB, attVT, bsum);
  h_gemm_kernel <<<dim3(4,16,7),  256, 0, stream>>>(x, expB, H);
  g_gemm_kernel <<<dim3(8,16),    256, 0, stream>>>(wA, bA, H, bsum, G);
  z_gemm_kernel <<<dim3(4,49,16), 256, 0, stream>>>(G, attVT, out);
}